// Round 5
// baseline (179.732 us; speedup 1.0000x reference)
//
#include <hip/hip_runtime.h>
#include <math.h>

#define BH 32
#define L  2048
#define D  64
#define SK 40
#define NT 40
#define NC 16          // key chunks for split-K attention
#define CK 128         // keys per chunk (NC*CK == L)
#define SCALE 0.125f

// ---- workspace layout (bytes) ----
#define WS_M      0                         // float[BH*L]          = 256 KB
#define WS_MTOP   262144                    // int[BH*NT]           = 5 KB
#define WS_VP     267264                    // float[256*64]        = 64 KB
#define WS_VM     332800                    // float[BH*D]          = 8 KB
#define WS_OPART  344064                    // float[BH*NC*NT*D]    = 5.24 MB
#define WS_MPART  5586944                   // float[BH*NC*NT]      = 80 KB
#define WS_LPART  5668864                   // float[BH*NC*NT]      = 80 KB

// =============== Kernel 1: fused sampled-scores + V-mean partials ===============
// Blocks [0,1024): kM. 64 queries/block, 4-lane groups (lane holds 16 q floats),
//   2 shuffles per sample instead of 4 (DS-pipe was the co-bottleneck).
// Blocks [1024,1280): V-mean partial sums (independent work, same launch).
__global__ __launch_bounds__(256) void kMV(const float* __restrict__ Q,
                                           const float* __restrict__ K,
                                           const float* __restrict__ V,
                                           const int* __restrict__ idx,
                                           float* __restrict__ M,
                                           float* __restrict__ Vp)
{
    __shared__ int   sidx[64 * SK];        // 10 KB
    __shared__ float red[256];

    int t = threadIdx.x;
    if (blockIdx.x < 1024) {
        // ---- kM path ----
        int b    = blockIdx.x;
        int xcd  = b & 7;
        int head = ((b >> 3) & 3) * 8 + xcd;   // XCD-swizzled head
        int qc   = b >> 5;                     // 0..31, 64-query chunk
        int l0   = qc * 64;

        // idx rows are contiguous: (l0+i/SK)*SK + i%SK == l0*SK + i
        for (int i = t; i < 64 * SK; i += 256) sidx[i] = idx[l0 * SK + i];
        __syncthreads();

        int wave = t >> 6, lane = t & 63;
        int g  = lane >> 2;                    // query group 0..15
        int dl = lane & 3;                     // quarter of D
        int lq = wave * 16 + g;                // 0..63
        int l  = l0 + lq;
        int qid = head * L + l;

        const float4* Q4 = reinterpret_cast<const float4*>(Q);
        float4 q0 = Q4[(size_t)qid * 16 + dl * 4 + 0];
        float4 q1 = Q4[(size_t)qid * 16 + dl * 4 + 1];
        float4 q2 = Q4[(size_t)qid * 16 + dl * 4 + 2];
        float4 q3 = Q4[(size_t)qid * 16 + dl * 4 + 3];
        const float4* Kb4 = reinterpret_cast<const float4*>(K) + (size_t)head * L * 16;

        float mx = -INFINITY, sm = 0.f;
        #pragma unroll 4
        for (int s = 0; s < SK; ++s) {
            int kr = sidx[lq * SK + s];
            const float4* kp = Kb4 + (size_t)kr * 16 + dl * 4;
            float4 k0 = kp[0], k1 = kp[1], k2 = kp[2], k3 = kp[3];
            float p = q0.x * k0.x + q0.y * k0.y + q0.z * k0.z + q0.w * k0.w
                    + q1.x * k1.x + q1.y * k1.y + q1.z * k1.z + q1.w * k1.w
                    + q2.x * k2.x + q2.y * k2.y + q2.z * k2.z + q2.w * k2.w
                    + q3.x * k3.x + q3.y * k3.y + q3.z * k3.z + q3.w * k3.w;
            p += __shfl_xor(p, 1, 64);
            p += __shfl_xor(p, 2, 64);
            mx = fmaxf(mx, p);
            sm += p;
        }
        if (dl == 0) M[qid] = mx - sm * (1.0f / (float)L);
    } else {
        // ---- V-mean partial path ----
        int b2 = blockIdx.x - 1024;            // 0..255 = bh*8 + c
        int bh = b2 >> 3, c = b2 & 7;
        int dl = t & 63;
        int gg = t >> 6;
        const float* Vb = V + (size_t)bh * L * D;
        float acc = 0.f;
        int base = c * 256 + gg * 64;
        for (int k = 0; k < 64; ++k) acc += Vb[(size_t)(base + k) * D + dl];
        red[t] = acc;
        __syncthreads();
        if (t < 64)
            Vp[b2 * 64 + dl] = red[dl] + red[64 + dl] + red[128 + dl] + red[192 + dl];
    }
}

// =============== Kernel 2: top-40 per head (radix select) + V-mean finalize ===============
__global__ __launch_bounds__(256) void kTopVm(const float* __restrict__ M,
                                              const float* __restrict__ Vp,
                                              int* __restrict__ Mtop,
                                              float* __restrict__ Vm)
{
    __shared__ unsigned int keys[L];
    __shared__ int hist[256];
    __shared__ int ssum[256];
    __shared__ int bsel;
    __shared__ unsigned int pref_s;
    __shared__ int krem_s;
    __shared__ int cnt_gt, cnt_eq;
    __shared__ int eqlist[64];

    int bh = blockIdx.x;
    int t  = threadIdx.x;

    // V-mean finalize (independent of the select)
    if (t < 64) {
        float s = 0.f;
        #pragma unroll
        for (int c = 0; c < 8; ++c) s += Vp[(bh * 8 + c) * 64 + t];
        Vm[bh * D + t] = s * (1.0f / (float)L);
    }

    for (int i = t; i < L; i += 256) {
        unsigned int u = __float_as_uint(M[bh * L + i]);
        keys[i] = (u & 0x80000000u) ? ~u : (u | 0x80000000u);
    }
    if (t == 0) { pref_s = 0u; krem_s = NT; cnt_gt = 0; cnt_eq = 0; }
    __syncthreads();

    #pragma unroll
    for (int shift = 24; shift >= 0; shift -= 8) {
        hist[t] = 0;
        __syncthreads();
        unsigned int pref = pref_s;
        for (int i = t; i < L; i += 256) {
            unsigned int k  = keys[i];
            unsigned int hi = (shift == 24) ? 0u : (k >> (shift + 8));
            if (hi == pref) atomicAdd(&hist[(k >> shift) & 0xFF], 1);
        }
        __syncthreads();
        ssum[t] = hist[t];                       // suffix-sum (inclusive)
        __syncthreads();
        for (int st = 1; st < 256; st <<= 1) {
            int v = (t + st < 256) ? ssum[t + st] : 0;
            __syncthreads();
            ssum[t] += v;
            __syncthreads();
        }
        int krem = krem_s;
        int excl = ssum[t] - hist[t];            // keys with byte > t under prefix
        if (excl < krem && excl + hist[t] >= krem) bsel = t;
        __syncthreads();
        if (t == 0) {
            int bb = bsel;
            krem_s = krem_s - (ssum[bb] - hist[bb]);
            pref_s = (pref_s << 8) | (unsigned int)bb;
        }
        __syncthreads();
    }

    unsigned int T = pref_s;
    int krem = krem_s;
    for (int i = t; i < L; i += 256) {
        unsigned int k = keys[i];
        if (k > T) {
            int p = atomicAdd(&cnt_gt, 1);
            Mtop[bh * NT + p] = i;               // set semantics; order irrelevant
        } else if (k == T) {
            int p = atomicAdd(&cnt_eq, 1);
            if (p < 64) eqlist[p] = i;
        }
    }
    __syncthreads();
    if (t == 0) {
        int base = cnt_gt;                       // == NT - krem
        int m = cnt_eq < 64 ? cnt_eq : 64;
        for (int q = 0; q < krem; ++q) {         // lowest-index ties, matching top_k
            int best = 0x7fffffff, bj = -1;
            for (int j = 0; j < m; ++j) if (eqlist[j] < best) { best = eqlist[j]; bj = j; }
            Mtop[bh * NT + base + q] = best;
            if (bj >= 0) eqlist[bj] = 0x7fffffff;
        }
    }
}

// =============== Kernel 3: split-K attention partials + V_mean broadcast fill ===============
// grid (NC, BH). Each block first fills its own 128-row output slice with V_mean
// (kCombine overwrites the top rows afterwards), then computes chunk partials.
__global__ __launch_bounds__(256, 2) void kAttnPart(const float* __restrict__ Q,
                                                    const float* __restrict__ K,
                                                    const float* __restrict__ V,
                                                    const int* __restrict__ Mtop,
                                                    const float* __restrict__ Vm,
                                                    float* __restrict__ Opart,
                                                    float* __restrict__ mpart,
                                                    float* __restrict__ lpart,
                                                    float* __restrict__ out)
{
    __shared__ float4 KV4[CK * 16];        // 32 KB, swizzled, reused K then V
    __shared__ float4 Qs4[NT * 16];        // 10 KB
    __shared__ float  S[NT * CK];          // 20 KB, scores then exp(P)
    __shared__ int    mrow[NT];
    __shared__ float  smax[NT], ssum[NT];

    int c = blockIdx.x, bh = blockIdx.y;
    int t = threadIdx.x;

    // ---- broadcast fill of this block's slice (async stores, overlap compute) ----
    {
        const float4* Vm4 = reinterpret_cast<const float4*>(Vm + bh * D);
        float4* outB = reinterpret_cast<float4*>(out) + ((size_t)bh * L + c * CK) * 16;
        #pragma unroll
        for (int k = 0; k < 8; ++k) { int i = t + k * 256; outB[i] = Vm4[i & 15]; }
    }

    if (t < NT) mrow[t] = Mtop[bh * NT + t];
    __syncthreads();

    // stage Q rows (gathered) and K chunk (swizzled)
    const float4* Qg = reinterpret_cast<const float4*>(Q) + (size_t)bh * L * 16;
    for (int i = t; i < NT * 16; i += 256) {
        int u = i >> 4, d4 = i & 15;
        Qs4[i] = Qg[(size_t)mrow[u] * 16 + d4];
    }
    const float4* Kg = reinterpret_cast<const float4*>(K) + ((size_t)bh * L + c * CK) * 16;
    for (int i = t; i < CK * 16; i += 256) {
        int j = i >> 4, d4 = i & 15;
        KV4[j * 16 + (d4 ^ (j & 15))] = Kg[i];
    }
    __syncthreads();

    // Phase A: S[u][j] = scale * q_u . k_j
    {
        int wave = t >> 6, lane = t & 63;
        int jh = wave & 1, uh = wave >> 1;       // j half, u half
        int j = jh * 64 + lane;
        float4 k4[16];
        #pragma unroll
        for (int d4 = 0; d4 < 16; ++d4) k4[d4] = KV4[j * 16 + (d4 ^ (j & 15))];
        for (int u = uh * 20; u < uh * 20 + 20; ++u) {
            float acc = 0.f;
            #pragma unroll
            for (int d4 = 0; d4 < 16; ++d4) {
                float4 q4 = Qs4[u * 16 + d4];
                acc += k4[d4].x * q4.x + k4[d4].y * q4.y
                     + k4[d4].z * q4.z + k4[d4].w * q4.w;
            }
            S[u * CK + j] = acc * SCALE;
        }
    }
    __syncthreads();

    // issue V loads early (latency overlaps softmax)
    const float4* Vg = reinterpret_cast<const float4*>(V) + ((size_t)bh * L + c * CK) * 16;
    float4 vreg[8];
    #pragma unroll
    for (int k = 0; k < 8; ++k) vreg[k] = Vg[t + k * 256];

    // chunk-local softmax: m,l per u; S <- exp(S - m)
    {
        int wave = t >> 6, lane = t & 63;
        for (int u = wave * 10; u < wave * 10 + 10; ++u) {
            float s0 = S[u * CK + lane], s1 = S[u * CK + 64 + lane];
            float m = fmaxf(s0, s1);
            #pragma unroll
            for (int o = 1; o < 64; o <<= 1) m = fmaxf(m, __shfl_xor(m, o, 64));
            float e0 = __expf(s0 - m), e1 = __expf(s1 - m);
            S[u * CK + lane] = e0; S[u * CK + 64 + lane] = e1;
            float l2 = e0 + e1;
            #pragma unroll
            for (int o = 1; o < 64; o <<= 1) l2 += __shfl_xor(l2, o, 64);
            if (lane == 0) { smax[u] = m; ssum[u] = l2; }
        }
    }
    __syncthreads();                       // S/m/l done, K-LDS reads done

    // overwrite LDS with V chunk (swizzled)
    #pragma unroll
    for (int k = 0; k < 8; ++k) {
        int i = t + k * 256;
        int j = i >> 4, d4 = i & 15;
        KV4[j * 16 + (d4 ^ (j & 15))] = vreg[k];
    }
    __syncthreads();

    // Phase B: O[u][d] = sum_j P[u][j] V[j][d], register-tiled.
    {
        int a = t >> 5, r = t & 31;
        int d4 = r >> 1, jh = r & 1;
        float4 acc[5];
        #pragma unroll
        for (int ui = 0; ui < 5; ++ui) acc[ui] = make_float4(0.f, 0.f, 0.f, 0.f);
        for (int jj = 0; jj < 64; ++jj) {
            int j = jh * 64 + jj;
            float4 v4 = KV4[j * 16 + (d4 ^ (j & 15))];
            #pragma unroll
            for (int ui = 0; ui < 5; ++ui) {
                float p = S[(a + 8 * ui) * CK + j];
                acc[ui].x += p * v4.x; acc[ui].y += p * v4.y;
                acc[ui].z += p * v4.z; acc[ui].w += p * v4.w;
            }
        }
        #pragma unroll
        for (int ui = 0; ui < 5; ++ui) {
            acc[ui].x += __shfl_xor(acc[ui].x, 1, 64);
            acc[ui].y += __shfl_xor(acc[ui].y, 1, 64);
            acc[ui].z += __shfl_xor(acc[ui].z, 1, 64);
            acc[ui].w += __shfl_xor(acc[ui].w, 1, 64);
        }
        if (jh == 0) {
            float4* Og = reinterpret_cast<float4*>(Opart) + ((size_t)(bh * NC + c) * NT) * 16;
            #pragma unroll
            for (int ui = 0; ui < 5; ++ui)
                Og[(a + 8 * ui) * 16 + d4] = acc[ui];
        }
    }
    if (t < NT) {
        mpart[(bh * NC + c) * NT + t] = smax[t];
        lpart[(bh * NC + c) * NT + t] = ssum[t];
    }
}

// =============== Kernel 4: combine partials, overwrite selected rows ===============
__global__ __launch_bounds__(64) void kCombine(const float* __restrict__ Opart,
                                               const float* __restrict__ mpart,
                                               const float* __restrict__ lpart,
                                               const int* __restrict__ Mtop,
                                               float* __restrict__ out)
{
    int u = blockIdx.x, bh = blockIdx.y, d = threadIdx.x;
    float gm = -INFINITY, den = 0.f, o = 0.f;
    for (int c = 0; c < NC; ++c) {
        int pi = (bh * NC + c) * NT + u;
        float mv = mpart[pi], lv = lpart[pi];
        float nm = fmaxf(gm, mv);
        float r1 = __expf(gm - nm), r2 = __expf(mv - nm);
        o   = o * r1 + r2 * Opart[(size_t)pi * D + d];
        den = den * r1 + r2 * lv;
        gm  = nm;
    }
    int qrow = Mtop[bh * NT + u];
    out[((size_t)bh * L + qrow) * D + d] = o / den;
}

extern "C" void kernel_launch(void* const* d_in, const int* in_sizes, int n_in,
                              void* d_out, int out_size, void* d_ws, size_t ws_size,
                              hipStream_t stream)
{
    const float* Q   = (const float*)d_in[0];
    const float* K   = (const float*)d_in[1];
    const float* V   = (const float*)d_in[2];
    const int*   idx = (const int*)d_in[3];
    float* out = (float*)d_out;

    char* ws = (char*)d_ws;
    float* M     = (float*)(ws + WS_M);
    int*   Mtop  = (int*)  (ws + WS_MTOP);
    float* Vp    = (float*)(ws + WS_VP);
    float* Vm    = (float*)(ws + WS_VM);
    float* Opart = (float*)(ws + WS_OPART);
    float* mpart = (float*)(ws + WS_MPART);
    float* lpart = (float*)(ws + WS_LPART);

    kMV      <<<1280, 256, 0, stream>>>(Q, K, V, idx, M, Vp);
    kTopVm   <<<BH, 256, 0, stream>>>(M, Vp, Mtop, Vm);
    kAttnPart<<<dim3(NC, BH), 256, 0, stream>>>(Q, K, V, Mtop, Vm, Opart, mpart, lpart, out);
    kCombine <<<dim3(NT, BH), 64, 0, stream>>>(Opart, mpart, lpart, Mtop, out);
}

// Round 8
// 165.505 us; speedup vs baseline: 1.0860x; 1.0860x over previous
//
#include <hip/hip_runtime.h>
#include <math.h>

#define BH 32
#define L  2048
#define D  64
#define SK 40
#define NT 40
#define NC 16          // key chunks for split-K attention
#define CK 128         // keys per chunk (NC*CK == L)
#define SP 129         // padded LDS stride for S (kills 4-way bank conflict)
#define SCALE 0.125f

// ---- workspace layout (bytes) ----
#define WS_M      0                  // float[BH*L]            = 256 KB
#define WS_MTOP   262144             // int[BH*NT]             = 5 KB
#define WS_VP     267264             // float[1024*64]         = 256 KB
#define WS_VM     529408             // float[BH*D]            = 8 KB
#define WS_QTOP   537600             // float[BH*NT*D]         = 320 KB
#define WS_OPART  865280             // float[BH*NC*NT*D]      = 5.24 MB
#define WS_MPART  6108160            // float[BH*NC*NT]        = 80 KB
#define WS_LPART  6190080            // float[BH*NC*NT]        = 80 KB

// DPP add: VALU-only cross-lane (no DS pipe). ctrl is a template constant.
// DPP direction: dest lane i reads src lane (i-N) mod 16 for row_ror:N.
// 0xB1 = quad_perm [1,0,3,2] (xor1), 0x4E = quad_perm [2,3,0,1] (xor2),
// 0x12C = row_ror:12 -> dest i <- src (i+4) mod 16 (valid at dl==0 of 8-groups).
template <int CTRL>
__device__ __forceinline__ float dpp_add(float x) {
    int y = __builtin_amdgcn_update_dpp(0, __float_as_int(x), CTRL, 0xF, 0xF, true);
    return x + __int_as_float(y);
}

// =============== Kernel 1: fused sampled-scores + V-mean partials ===============
// 1024 blocks x 512 threads = exactly 4 blocks/CU (full occupancy cap).
// 8 queries/wave (8-lane groups, 2 float4 of Q per lane); dot-reduce via DPP.
__global__ __launch_bounds__(512) void kMV(const float* __restrict__ Q,
                                           const float* __restrict__ K,
                                           const float* __restrict__ V,
                                           const int* __restrict__ idx,
                                           float* __restrict__ M,
                                           float* __restrict__ Vp)
{
    __shared__ int   sidx[64 * SK];    // 10 KB
    __shared__ float red[512];

    int t    = threadIdx.x;
    int b    = blockIdx.x;
    int head = ((b >> 3) & 3) * 8 + (b & 7);   // XCD-swizzled head
    int qc   = b >> 5;                         // 0..31
    int l0   = qc * 64;

    // ---- V-mean partial for rows l0..l0+63 of this head ----
    {
        int d = t & 63, r = t >> 6;            // r = 0..7
        const float* Vb = V + ((size_t)head * L + l0 + r * 8) * D + d;
        float acc = 0.f;
        #pragma unroll
        for (int k = 0; k < 8; ++k) acc += Vb[(size_t)k * D];
        red[t] = acc;
    }
    // ---- stage index rows (contiguous) ----
    for (int i = t; i < 64 * SK; i += 512) sidx[i] = idx[l0 * SK + i];
    __syncthreads();
    if (t < 64) {
        float s = 0.f;
        #pragma unroll
        for (int rr = 0; rr < 8; ++rr) s += red[t + rr * 64];
        Vp[(head * 32 + qc) * 64 + t] = s;
    }

    // ---- sampled-scores path ----
    int wave = t >> 6, lane = t & 63;
    int g  = lane >> 3;                        // query within wave, 0..7
    int dl = lane & 7;                         // octant of D
    int lq = wave * 8 + g;                     // 0..63
    size_t qid = (size_t)head * L + (l0 + lq);

    const float4* Q4 = reinterpret_cast<const float4*>(Q);
    float4 q0 = Q4[qid * 16 + dl * 2 + 0];
    float4 q1 = Q4[qid * 16 + dl * 2 + 1];
    const float4* Kb4 = reinterpret_cast<const float4*>(K) + (size_t)head * L * 16;

    float mx = -INFINITY, sm = 0.f;
    #pragma unroll 4
    for (int s = 0; s < SK; ++s) {
        int kr = sidx[lq * SK + s];
        const float4* kp = Kb4 + (size_t)kr * 16 + dl * 2;
        float4 k0 = kp[0], k1 = kp[1];
        float p = q0.x * k0.x + q0.y * k0.y + q0.z * k0.z + q0.w * k0.w
                + q1.x * k1.x + q1.y * k1.y + q1.z * k1.z + q1.w * k1.w;
        p = dpp_add<0xB1>(p);                  // + lane^1
        p = dpp_add<0x4E>(p);                  // + lane^2
        p = dpp_add<0x12C>(p);                 // + lane+4 (row_ror:12), valid at dl==0
        mx = fmaxf(mx, p);
        sm += p;
    }
    if (dl == 0) M[qid] = mx - sm * (1.0f / (float)L);
}

// =============== Kernel 2: top-40 (radix select) + V-mean finalize + Q gather ===============
__global__ __launch_bounds__(256) void kTopVm(const float* __restrict__ M,
                                              const float* __restrict__ Vp,
                                              const float* __restrict__ Q,
                                              int* __restrict__ Mtop,
                                              float* __restrict__ Vm,
                                              float* __restrict__ Qtop)
{
    __shared__ unsigned int keys[L];
    __shared__ int hist[256];
    __shared__ int ssum[256];
    __shared__ int bsel;
    __shared__ unsigned int pref_s;
    __shared__ int krem_s;
    __shared__ int cnt_gt, cnt_eq;
    __shared__ int eqlist[64];
    __shared__ int stop[NT];

    int bh = blockIdx.x;
    int t  = threadIdx.x;

    if (t < 64) {
        float s = 0.f;
        #pragma unroll
        for (int c = 0; c < 32; ++c) s += Vp[(bh * 32 + c) * 64 + t];
        Vm[bh * D + t] = s * (1.0f / (float)L);
    }

    for (int i = t; i < L; i += 256) {
        unsigned int u = __float_as_uint(M[bh * L + i]);
        keys[i] = (u & 0x80000000u) ? ~u : (u | 0x80000000u);
    }
    if (t == 0) { pref_s = 0u; krem_s = NT; cnt_gt = 0; cnt_eq = 0; }
    __syncthreads();

    #pragma unroll
    for (int shift = 24; shift >= 0; shift -= 8) {
        hist[t] = 0;
        __syncthreads();
        unsigned int pref = pref_s;
        for (int i = t; i < L; i += 256) {
            unsigned int k  = keys[i];
            unsigned int hi = (shift == 24) ? 0u : (k >> (shift + 8));
            if (hi == pref) atomicAdd(&hist[(k >> shift) & 0xFF], 1);
        }
        __syncthreads();
        ssum[t] = hist[t];
        __syncthreads();
        for (int st = 1; st < 256; st <<= 1) {
            int v = (t + st < 256) ? ssum[t + st] : 0;
            __syncthreads();
            ssum[t] += v;
            __syncthreads();
        }
        int krem = krem_s;
        int excl = ssum[t] - hist[t];
        if (excl < krem && excl + hist[t] >= krem) bsel = t;
        __syncthreads();
        if (t == 0) {
            int bb = bsel;
            krem_s = krem_s - (ssum[bb] - hist[bb]);
            pref_s = (pref_s << 8) | (unsigned int)bb;
        }
        __syncthreads();
    }

    unsigned int T = pref_s;
    int krem = krem_s;
    for (int i = t; i < L; i += 256) {
        unsigned int k = keys[i];
        if (k > T) {
            int p = atomicAdd(&cnt_gt, 1);
            Mtop[bh * NT + p] = i;
            stop[p] = i;
        } else if (k == T) {
            int p = atomicAdd(&cnt_eq, 1);
            if (p < 64) eqlist[p] = i;
        }
    }
    __syncthreads();
    if (t == 0) {
        int base = cnt_gt;
        int m = cnt_eq < 64 ? cnt_eq : 64;
        for (int q = 0; q < krem; ++q) {
            int best = 0x7fffffff, bj = -1;
            for (int j = 0; j < m; ++j) if (eqlist[j] < best) { best = eqlist[j]; bj = j; }
            Mtop[bh * NT + base + q] = best;
            stop[base + q] = best;
            if (bj >= 0) eqlist[bj] = 0x7fffffff;
        }
    }
    __syncthreads();
    // gather selected Q rows into compact Qtop (read wave-uniform in kAttnPart)
    const float4* Qg = reinterpret_cast<const float4*>(Q) + (size_t)bh * L * 16;
    float4* Qt = reinterpret_cast<float4*>(Qtop) + (size_t)bh * NT * 16;
    for (int i = t; i < NT * 16; i += 256)
        Qt[i] = Qg[(size_t)stop[i >> 4] * 16 + (i & 15)];
}

// =============== Kernel 3: split-K attention partials + V_mean broadcast fill ===============
// grid (NC, BH). K rows live in registers (lane owns j=lane and j=lane+64);
// Q via wave-uniform loads; in-register softmax; only V and exp(S) round-trip
// through LDS. One barrier.
__global__ __launch_bounds__(256, 2) void kAttnPart(const float* __restrict__ Qtop,
                                                    const float* __restrict__ K,
                                                    const float* __restrict__ V,
                                                    const float* __restrict__ Vm,
                                                    float* __restrict__ Opart,
                                                    float* __restrict__ mpart,
                                                    float* __restrict__ lpart,
                                                    float* __restrict__ out)
{
    __shared__ float4 V4[CK * 16];         // 32 KB, swizzled
    __shared__ float  S[NT * SP];          // 20.6 KB, exp(scores)
    __shared__ float  smax[NT], ssum[NT];

    int c = blockIdx.x, bh = blockIdx.y;
    int t = threadIdx.x;

    // ---- broadcast fill of this block's output slice ----
    {
        const float4* Vm4 = reinterpret_cast<const float4*>(Vm + bh * D);
        float4* outB = reinterpret_cast<float4*>(out) + ((size_t)bh * L + c * CK) * 16;
        #pragma unroll
        for (int k = 0; k < 8; ++k) { int i = t + k * 256; outB[i] = Vm4[i & 15]; }
    }

    // ---- V chunk loads (coalesced, into regs; LDS write after phase A) ----
    const float4* Vg = reinterpret_cast<const float4*>(V) + ((size_t)bh * L + c * CK) * 16;
    float4 vreg[8];
    #pragma unroll
    for (int k = 0; k < 8; ++k) vreg[k] = Vg[t + k * 256];

    // ---- K rows into registers: lane owns j0 = lane, j1 = 64+lane ----
    int w    = __builtin_amdgcn_readfirstlane(t) >> 6;   // scalar wave id
    int lane = t & 63;
    const float4* Kg = reinterpret_cast<const float4*>(K) + ((size_t)bh * L + c * CK) * 16;
    float4 k0[16], k1[16];
    #pragma unroll
    for (int d4 = 0; d4 < 16; ++d4) {
        k0[d4] = Kg[(size_t)lane * 16 + d4];
        k1[d4] = Kg[(size_t)(64 + lane) * 16 + d4];
    }

    // ---- Phase A: wave w scores its 10 queries against all 128 keys ----
    const float* Qb = Qtop + ((size_t)bh * NT + w * 10) * D;   // wave-uniform
    float p0[10], p1[10];
    #pragma unroll
    for (int i = 0; i < 10; ++i) {
        const float* qrow = Qb + i * D;
        float a0 = 0.f, a1 = 0.f;
        #pragma unroll
        for (int d4 = 0; d4 < 16; ++d4) {
            float4 q4 = *reinterpret_cast<const float4*>(qrow + d4 * 4);
            a0 += q4.x * k0[d4].x + q4.y * k0[d4].y + q4.z * k0[d4].z + q4.w * k0[d4].w;
            a1 += q4.x * k1[d4].x + q4.y * k1[d4].y + q4.z * k1[d4].z + q4.w * k1[d4].w;
        }
        p0[i] = a0 * SCALE; p1[i] = a1 * SCALE;
    }

    // ---- in-register softmax per u; write exp(S) to LDS ----
    #pragma unroll
    for (int i = 0; i < 10; ++i) {
        int u = w * 10 + i;
        float m = fmaxf(p0[i], p1[i]);
        #pragma unroll
        for (int o = 1; o < 64; o <<= 1) m = fmaxf(m, __shfl_xor(m, o, 64));
        float e0 = __expf(p0[i] - m), e1 = __expf(p1[i] - m);
        float l2 = e0 + e1;
        #pragma unroll
        for (int o = 1; o < 64; o <<= 1) l2 += __shfl_xor(l2, o, 64);
        S[u * SP + lane]      = e0;
        S[u * SP + 64 + lane] = e1;
        if (lane == 0) { smax[u] = m; ssum[u] = l2; }
    }

    // ---- V -> LDS (swizzled) ----
    #pragma unroll
    for (int k = 0; k < 8; ++k) {
        int i = t + k * 256;
        int j = i >> 4, d4 = i & 15;
        V4[j * 16 + (d4 ^ (j & 15))] = vreg[k];
    }
    __syncthreads();

    // ---- Phase B: O[u][d] = sum_j P[u][j] V[j][d], register-tiled ----
    {
        int a = t >> 5, r = t & 31;
        int d4 = r >> 1, jh = r & 1;
        float4 acc[5];
        #pragma unroll
        for (int ui = 0; ui < 5; ++ui) acc[ui] = make_float4(0.f, 0.f, 0.f, 0.f);
        for (int jj = 0; jj < 64; ++jj) {
            int j = jh * 64 + jj;
            float4 v4 = V4[j * 16 + (d4 ^ (j & 15))];
            #pragma unroll
            for (int ui = 0; ui < 5; ++ui) {
                float p = S[(a + 8 * ui) * SP + j];
                acc[ui].x += p * v4.x; acc[ui].y += p * v4.y;
                acc[ui].z += p * v4.z; acc[ui].w += p * v4.w;
            }
        }
        #pragma unroll
        for (int ui = 0; ui < 5; ++ui) {       // combine jh pairs via quad_perm xor1
            acc[ui].x = dpp_add<0xB1>(acc[ui].x);
            acc[ui].y = dpp_add<0xB1>(acc[ui].y);
            acc[ui].z = dpp_add<0xB1>(acc[ui].z);
            acc[ui].w = dpp_add<0xB1>(acc[ui].w);
        }
        if (jh == 0) {
            float4* Og = reinterpret_cast<float4*>(Opart) + ((size_t)(bh * NC + c) * NT) * 16;
            #pragma unroll
            for (int ui = 0; ui < 5; ++ui)
                Og[(a + 8 * ui) * 16 + d4] = acc[ui];
        }
    }
    if (t < NT) {
        mpart[(bh * NC + c) * NT + t] = smax[t];
        lpart[(bh * NC + c) * NT + t] = ssum[t];
    }
}

// =============== Kernel 4: combine partials, overwrite selected rows ===============
__global__ __launch_bounds__(64) void kCombine(const float* __restrict__ Opart,
                                               const float* __restrict__ mpart,
                                               const float* __restrict__ lpart,
                                               const int* __restrict__ Mtop,
                                               float* __restrict__ out)
{
    int u = blockIdx.x, bh = blockIdx.y, d = threadIdx.x;
    float gm = -INFINITY, den = 0.f, o = 0.f;
    for (int c = 0; c < NC; ++c) {
        int pi = (bh * NC + c) * NT + u;
        float mv = mpart[pi], lv = lpart[pi];
        float nm = fmaxf(gm, mv);
        float r1 = __expf(gm - nm), r2 = __expf(mv - nm);
        o   = o * r1 + r2 * Opart[(size_t)pi * D + d];
        den = den * r1 + r2 * lv;
        gm  = nm;
    }
    int qrow = Mtop[bh * NT + u];
    out[((size_t)bh * L + qrow) * D + d] = o / den;
}

extern "C" void kernel_launch(void* const* d_in, const int* in_sizes, int n_in,
                              void* d_out, int out_size, void* d_ws, size_t ws_size,
                              hipStream_t stream)
{
    const float* Q   = (const float*)d_in[0];
    const float* K   = (const float*)d_in[1];
    const float* V   = (const float*)d_in[2];
    const int*   idx = (const int*)d_in[3];
    float* out = (float*)d_out;

    char* ws = (char*)d_ws;
    float* M     = (float*)(ws + WS_M);
    int*   Mtop  = (int*)  (ws + WS_MTOP);
    float* Vp    = (float*)(ws + WS_VP);
    float* Vm    = (float*)(ws + WS_VM);
    float* Qtop  = (float*)(ws + WS_QTOP);
    float* Opart = (float*)(ws + WS_OPART);
    float* mpart = (float*)(ws + WS_MPART);
    float* lpart = (float*)(ws + WS_LPART);

    kMV      <<<1024, 512, 0, stream>>>(Q, K, V, idx, M, Vp);
    kTopVm   <<<BH, 256, 0, stream>>>(M, Vp, Q, Mtop, Vm, Qtop);
    kAttnPart<<<dim3(NC, BH), 256, 0, stream>>>(Qtop, K, V, Vm, Opart, mpart, lpart, out);
    kCombine <<<dim3(NT, BH), 64, 0, stream>>>(Opart, mpart, lpart, Mtop, out);
}